// Round 9
// baseline (2996.644 us; speedup 1.0000x reference)
//
#include <hip/hip_runtime.h>
#include <hip/hip_bf16.h>

// LSTM decoder B=256, T=512, H=1024 — persistent fp16 MFMA, v7.
// = v6 (2.64 ms) with the monolithic 32-WG m-group barrier replaced by
// per-producer dataflow flags:
//   * producer WG (gm,jt2) publishes flag[gm][jt2]=t+1 after its h-store drains
//   * consumer wave k4 waits flag(gm, k4*8+ch) >= t before using chunk ch's A
//   * flags batch-loaded at step start (1 overlapped LLC RT), lookahead checks
//     hidden under MFMA issue; spin only engages when a producer lags.
// WAR safety (2 h-buffers): the WG reduction __syncthreads joins waves that
// collectively waited on ALL 32 group flags >= t, so every member's t-1 reads
// precede any member's t-epilogue write. Forward dataflow -> no deadlock.

#define BB 256
#define TT 512
#define HH 1024

typedef __attribute__((ext_vector_type(8))) short short8;
typedef __attribute__((ext_vector_type(8))) _Float16 half8;
typedef __attribute__((ext_vector_type(4))) float float4v;

#define HP_U64 ((size_t)65536)   // u64 per h buffer: 256 U-units x 256 rows

__device__ __forceinline__ float sigf(float x) { return 1.0f / (1.0f + __expf(-x)); }
__device__ __forceinline__ float tanhff(float x) {
    return 1.0f - 2.0f / (__expf(2.0f * x) + 1.0f);
}
__device__ __forceinline__ unsigned ld_flag(unsigned int* p) {
    return __hip_atomic_load(p, __ATOMIC_RELAXED, __HIP_MEMORY_SCOPE_AGENT);
}

// ---- pack W_hh (4096x1024 f32) -> fp16 B-fragment order ----
// Wp[jt2(32)][kc(32)][g(4)][nt(2)][lane(64)][8] ; per-jt2 block = 256 KB
__global__ __launch_bounds__(256) void pack_w(const float* __restrict__ W_hh,
                                              unsigned short* __restrict__ Wp) {
    int fid = blockIdx.x * 256 + threadIdx.x;   // 0..524287
    int lane = fid & 63;
    int nt = (fid >> 6) & 1;
    int g = (fid >> 7) & 3;
    int kc = (fid >> 9) & 31;
    int jt2 = fid >> 14;
    int j = jt2 * 32 + nt * 16 + (lane & 15);
    int row = g * HH + j;
    int k = kc * 32 + (lane >> 4) * 8;
    const float* src = W_hh + (size_t)row * HH + k;
    union { _Float16 h[8]; short8 s; } u;
#pragma unroll
    for (int e = 0; e < 8; ++e) u.h[e] = (_Float16)src[e];
    *(short8*)(Wp + (size_t)fid * 8) = u.s;
}

// ---- h0 -> fp16 fragment layout in buffer 0; zero dataflow flags ----
__global__ __launch_bounds__(256) void prep_state(const float* __restrict__ h0,
                                                  unsigned long long* __restrict__ hb0,
                                                  unsigned int* __restrict__ cnt) {
    int gid = blockIdx.x * 256 + threadIdx.x;   // 0..65535
    int r = gid & 255;
    int U = gid >> 8;
    int kb = (U >> 3) * 32 + ((U >> 1) & 3) * 8 + (U & 1) * 4;
    float4 v = *(const float4*)(h0 + (size_t)r * HH + kb);
    union { _Float16 h[4]; unsigned long long u; } x;
    x.h[0] = (_Float16)v.x; x.h[1] = (_Float16)v.y;
    x.h[2] = (_Float16)v.z; x.h[3] = (_Float16)v.w;
    hb0[(size_t)U * 256 + r] = x.u;
    if (blockIdx.x < 32) cnt[blockIdx.x * 256 + threadIdx.x] = 0;   // 32 KB flags
}

// ---- persistent LSTM kernel: all 512 steps + final FC ----
__global__ __launch_bounds__(512, 1) void lstm_persist(
    const float* __restrict__ y_hist,
    const float* __restrict__ W_ih,           // (4096) flat
    const float* __restrict__ b_ih,
    const float* __restrict__ b_hh,
    const float* __restrict__ c0,             // (B,H) f32
    const float* __restrict__ W_fc,           // (H)
    const float* __restrict__ b_fc,           // (1)
    const unsigned short* __restrict__ Wp,    // packed fp16 W fragments
    unsigned long long* hbase,                // 2 buffers x HP_U64 u64
    unsigned int* cnt,                        // flags[gm(8)][jt2(32)] on 128B lines
    float* __restrict__ out)
{
    __shared__ __align__(16) unsigned short Wlds[65536];   // 128 KB: gates 0,1
    __shared__ __align__(16) float scr[8192];              // 32 KB: 4 regions x 2048
    // 160 KiB exactly -> 1 WG/CU; grid=256 => all WGs co-resident

    const int tid = threadIdx.x;
    const int lane = tid & 63;
    const int wv = tid >> 6;
    const int m2 = wv & 1;                     // m half (16 rows)
    const int k4 = wv >> 1;                    // K quarter (256 k)
    const int bid = blockIdx.x;
    const int gm = bid >> 5;                   // m-group 0..7 (32 rows)
    const int jt2 = bid & 31;                  // 32-j tile

    const unsigned short* WpJ = Wp + (size_t)jt2 * 131072;

    // --- LDS: gates 0,1 fragments (all kc) ---
    for (int f = tid; f < 8192; f += 512) {
        int kc = f >> 8, g = (f >> 7) & 1, low = f & 127;
        *(short8*)&Wlds[(size_t)((kc * 2 + g) * 128 + low) * 8] =
            *(const short8*)(WpJ + (size_t)((kc * 4 + g) * 128 + low) * 8);
    }
    // --- registers: gates 2,3 fragments for this wave's K-quarter ---
    half8 Breg[8][2][2];   // [kc_l][g-2][nt]
#pragma unroll
    for (int kc_l = 0; kc_l < 8; ++kc_l) {
        int kc = k4 * 8 + kc_l;
#pragma unroll
        for (int g2 = 0; g2 < 2; ++g2)
#pragma unroll
            for (int nt = 0; nt < 2; ++nt)
                Breg[kc_l][g2][nt] = *(const half8*)
                    (WpJ + (size_t)((((kc * 4 + 2 + g2) * 2 + nt) * 64 + lane)) * 8);
    }

    // --- A addressing ---
    const int blk = gm * 2 + m2;               // 16-row block 0..15
    const int q = lane >> 4;
    const size_t abase = (size_t)blk * 16 + (lane & 15);
    const size_t qoff = (size_t)q * 512;

    // --- dataflow flags: this wave's 8 producers; own publish slot ---
    unsigned int* fbase = cnt + (size_t)gm * 32 * 32;        // group base
    unsigned int* fprod[8];
#pragma unroll
    for (int p = 0; p < 8; ++p) fprod[p] = fbase + (k4 * 8 + p) * 32;
    unsigned int* fmine = fbase + jt2 * 32;

    // --- epilogue constants (tid<256: cell = 1 row x 4 j) ---
    const int em = tid & 31;
    const int jq = (tid >> 5) & 7;
    const int M = gm * 32 + em;
    float wi_[4][4], bs_[4][4], c_[4];
    if (tid < 256) {
#pragma unroll
        for (int g = 0; g < 4; ++g)
#pragma unroll
            for (int jj = 0; jj < 4; ++jj) {
                int j = jt2 * 32 + jq * 4 + jj;
                wi_[g][jj] = W_ih[g * HH + j];
                bs_[g][jj] = b_ih[g * HH + j] + b_hh[g * HH + j];
            }
#pragma unroll
        for (int jj = 0; jj < 4; ++jj)
            c_[jj] = c0[(size_t)M * HH + jt2 * 32 + jq * 4 + jj];
    }
    const size_t sunit = (size_t)(jt2 * 8 + jq) * 256 + (M >> 4) * 16 + (M & 15);

    __syncthreads();   // Wlds visible

    const int ml = q * 4;                      // local row base within 16-row tile

    for (int t = 0; t < TT; ++t) {
        const unsigned long long* hR = hbase + (size_t)(t & 1) * HP_U64;
        unsigned long long* hW = hbase + (size_t)((t + 1) & 1) * HP_U64;
        const unsigned need = (unsigned)t;

        // --- batch-load all 8 producer flags (overlapped LLC RTs) ---
        unsigned fl[8];
#pragma unroll
        for (int p = 0; p < 8; ++p) fl[p] = ld_flag(fprod[p]);

        float4v acc[8] = {{0.f,0.f,0.f,0.f},{0.f,0.f,0.f,0.f},{0.f,0.f,0.f,0.f},
                          {0.f,0.f,0.f,0.f},{0.f,0.f,0.f,0.f},{0.f,0.f,0.f,0.f},
                          {0.f,0.f,0.f,0.f},{0.f,0.f,0.f,0.f}};

        // --- prologue: wait flags 0-3, issue A ring chunks 0-3 ---
        unsigned long long ring[4][2];
#pragma unroll
        for (int p = 0; p < 4; ++p) {
            while (fl[p] < need) { __builtin_amdgcn_s_sleep(1); fl[p] = ld_flag(fprod[p]); }
        }
        asm volatile("" ::: "memory");
#pragma unroll
        for (int p = 0; p < 4; ++p) {
            size_t ua = (size_t)(k4 * 8 + p) * 2048 + qoff + abase;
            ring[p][0] = __hip_atomic_load((unsigned long long*)&hR[ua],
                                           __ATOMIC_RELAXED, __HIP_MEMORY_SCOPE_AGENT);
            ring[p][1] = __hip_atomic_load((unsigned long long*)&hR[ua + 256],
                                           __ATOMIC_RELAXED, __HIP_MEMORY_SCOPE_AGENT);
        }

#pragma unroll
        for (int ch = 0; ch < 8; ++ch) {
            union { unsigned long long u[2]; half8 h; } af;
            af.u[0] = ring[ch & 3][0];
            af.u[1] = ring[ch & 3][1];
            const int kc = k4 * 8 + ch;
#pragma unroll
            for (int g = 0; g < 2; ++g)
#pragma unroll
                for (int nt = 0; nt < 2; ++nt) {
                    half8 bh = *(const half8*)
                        &Wlds[(size_t)((kc * 2 + g) * 128 + nt * 64 + lane) * 8];
                    acc[g * 2 + nt] =
                        __builtin_amdgcn_mfma_f32_16x16x32_f16(af.h, bh, acc[g * 2 + nt], 0, 0, 0);
                }
#pragma unroll
            for (int g2 = 0; g2 < 2; ++g2)
#pragma unroll
                for (int nt = 0; nt < 2; ++nt)
                    acc[(2 + g2) * 2 + nt] =
                        __builtin_amdgcn_mfma_f32_16x16x32_f16(af.h, Breg[ch][g2][nt],
                                                               acc[(2 + g2) * 2 + nt], 0, 0, 0);
            // prefetch chunk ch+4 after waiting its producer (usually no spin)
            if (ch < 4) {
                const int p4 = ch + 4;
                while (fl[p4] < need) { __builtin_amdgcn_s_sleep(1); fl[p4] = ld_flag(fprod[p4]); }
                asm volatile("" ::: "memory");
                size_t ua = (size_t)(k4 * 8 + p4) * 2048 + qoff + abase;
                ring[ch & 3][0] = __hip_atomic_load((unsigned long long*)&hR[ua],
                                                    __ATOMIC_RELAXED, __HIP_MEMORY_SCOPE_AGENT);
                ring[ch & 3][1] = __hip_atomic_load((unsigned long long*)&hR[ua + 256],
                                                    __ATOMIC_RELAXED, __HIP_MEMORY_SCOPE_AGENT);
            }
        }

        // --- 4-way k-reduction, 2 rounds in 32 KB scratch (v6-proven) ---
        if (k4 >= 2) {
            int rb = (m2 * 2 + (k4 & 1)) * 2048;
#pragma unroll
            for (int a = 0; a < 8; ++a) {
                int n = (a >> 1) * 32 + (a & 1) * 16 + (lane & 15);
                *(float4v*)&scr[rb + n * 16 + (ml ^ ((n & 3) << 2))] = acc[a];
            }
        }
        __syncthreads();
        if (k4 < 2) {
            int rb = (m2 * 2 + k4) * 2048;
#pragma unroll
            for (int a = 0; a < 8; ++a) {
                int n = (a >> 1) * 32 + (a & 1) * 16 + (lane & 15);
                acc[a] += *(const float4v*)&scr[rb + n * 16 + (ml ^ ((n & 3) << 2))];
            }
            if (k4 == 1) {
#pragma unroll
                for (int a = 0; a < 8; ++a) {
                    int n = (a >> 1) * 32 + (a & 1) * 16 + (lane & 15);
                    *(float4v*)&scr[(m2 * 2 + 1) * 2048 + n * 16 + (ml ^ ((n & 3) << 2))] = acc[a];
                }
            }
        }
        __syncthreads();
        if (k4 == 0) {
#pragma unroll
            for (int a = 0; a < 8; ++a) {
                int n = (a >> 1) * 32 + (a & 1) * 16 + (lane & 15);
                int sw = n * 16 + (ml ^ ((n & 3) << 2));
                acc[a] += *(const float4v*)&scr[(m2 * 2 + 1) * 2048 + sw];
                *(float4v*)&scr[(m2 * 2) * 2048 + sw] = acc[a];
            }
        }
        __syncthreads();

        // --- epilogue (tid<256): 1 row x 4 j; one u64 sc0sc1 store ---
        if (tid < 256) {
            float x = y_hist[(size_t)M * TT + t];
            int rbase = (em >> 4) * 2 * 2048;
            union { _Float16 h[4]; unsigned long long u; } hv;
#pragma unroll
            for (int jj = 0; jj < 4; ++jj) {
                int msw = (em & 15) ^ (jj << 2);
                int nb = jq * 4 + jj;
                float gi = scr[rbase + (0 * 32 + nb) * 16 + msw] + x * wi_[0][jj] + bs_[0][jj];
                float gf = scr[rbase + (1 * 32 + nb) * 16 + msw] + x * wi_[1][jj] + bs_[1][jj];
                float gg = scr[rbase + (2 * 32 + nb) * 16 + msw] + x * wi_[2][jj] + bs_[2][jj];
                float go = scr[rbase + (3 * 32 + nb) * 16 + msw] + x * wi_[3][jj] + bs_[3][jj];
                float cn = sigf(gf) * c_[jj] + sigf(gi) * tanhff(gg);
                float hn = sigf(go) * tanhff(cn);
                c_[jj] = cn;
                hv.h[jj] = (_Float16)hn;
            }
            asm volatile("global_store_dwordx2 %0, %1, off sc0 sc1"
                         : : "v"((void*)(hW + sunit)), "v"(hv.u) : "memory");
        }

        // --- drain own stores, join WG, publish flag; no rendezvous spin ---
        asm volatile("s_waitcnt vmcnt(0)" ::: "memory");
        __syncthreads();
        if (tid == 0)
            __hip_atomic_store(fmine, (unsigned)(t + 1),
                               __ATOMIC_RELAXED, __HIP_MEMORY_SCOPE_AGENT);
    }

    // --- final FC (h final in buffer 0): jt2==0 WGs only ---
    if (jt2 == 0) {
        // wait until all 32 producers of this group have published step TT
        unsigned int* fw = fbase + (wv * 4) * 32;
#pragma unroll
        for (int p = 0; p < 4; ++p) {
            unsigned int* fp = fbase + (wv * 4 + p) * 32;
            while (ld_flag(fp) < (unsigned)TT) __builtin_amdgcn_s_sleep(1);
        }
        (void)fw;
        asm volatile("" ::: "memory");
        __syncthreads();
        if (k4 == 0) {
            const unsigned long long* hF = hbase;   // buffer 0
#pragma unroll 1
            for (int rr = 0; rr < 16; ++rr) {
                int row = gm * 32 + m2 * 16 + rr;
                int boff = (row >> 4) * 16 + (row & 15);
                float s = 0.f;
#pragma unroll 1
                for (int uu = 0; uu < 4; ++uu) {
                    int U = uu * 64 + lane;
                    unsigned long long u = __hip_atomic_load(
                        (unsigned long long*)&hF[(size_t)U * 256 + boff],
                        __ATOMIC_RELAXED, __HIP_MEMORY_SCOPE_AGENT);
                    int kb = (U >> 3) * 32 + ((U >> 1) & 3) * 8 + (U & 1) * 4;
                    union { _Float16 h[4]; unsigned long long x; } v;
                    v.x = u;
                    float4 wf = *(const float4*)(W_fc + kb);
                    s += (float)v.h[0] * wf.x + (float)v.h[1] * wf.y +
                         (float)v.h[2] * wf.z + (float)v.h[3] * wf.w;
                }
#pragma unroll
                for (int off = 32; off > 0; off >>= 1) s += __shfl_xor(s, off);
                if (lane == 0) out[row] = s + b_fc[0];
            }
        }
    }
}

extern "C" void kernel_launch(void* const* d_in, const int* in_sizes, int n_in,
                              void* d_out, int out_size, void* d_ws, size_t ws_size,
                              hipStream_t stream) {
    const float* y_hist = (const float*)d_in[0];
    const float* W_ih   = (const float*)d_in[1];
    const float* W_hh   = (const float*)d_in[2];
    const float* b_ih   = (const float*)d_in[3];
    const float* b_hh   = (const float*)d_in[4];
    const float* W_fc   = (const float*)d_in[5];
    const float* b_fc   = (const float*)d_in[6];
    const float* h0     = (const float*)d_in[7];
    const float* c0     = (const float*)d_in[8];
    float* out = (float*)d_out;

    // ws: Wp fp16 (8 MB) | h buffers 2 x 512 KB | flags (32 KB)
    unsigned short* Wp = (unsigned short*)d_ws;
    unsigned long long* hbase = (unsigned long long*)(Wp + (size_t)4194304);
    unsigned int* cnt = (unsigned int*)(hbase + 2 * HP_U64);

    pack_w<<<2048, 256, 0, stream>>>(W_hh, Wp);
    prep_state<<<256, 256, 0, stream>>>(h0, hbase, cnt);

    // 256 WGs x 512 threads, 160 KiB LDS -> 1 WG/CU, all co-resident
    lstm_persist<<<256, 512, 0, stream>>>(y_hist, W_ih, b_ih, b_hh, c0, W_fc, b_fc,
                                          Wp, hbase, cnt, out);
}

// Round 10
// 2525.616 us; speedup vs baseline: 1.1865x; 1.1865x over previous
//
#include <hip/hip_runtime.h>
#include <hip/hip_bf16.h>

// LSTM decoder B=256, T=512, H=1024 — persistent fp16 MFMA, v8.
// = v6 (2.64 ms, proven) + three critical-path cuts:
//   1) 8-deep A prefetch ring: all 16 chunk-loads issued in prologue ->
//      single LLC latency batch instead of two.
//   2) epilogue spread over all 512 threads (2 j per thread); per-wave h-store
//      is 64 lanes x 4B contiguous = full 256B lines (RMW-free, coalesced).
//   3) y_hist x prefetched at step start, hidden under the K-loop.
// Barrier: v6 monolithic m-group counter (R9 showed per-producer flags lose).

#define BB 256
#define TT 512
#define HH 1024

typedef __attribute__((ext_vector_type(8))) short short8;
typedef __attribute__((ext_vector_type(8))) _Float16 half8;
typedef __attribute__((ext_vector_type(4))) float float4v;

#define HP_U64 ((size_t)65536)   // u64 per h buffer: 256 U-units x 256 rows

__device__ __forceinline__ float sigf(float x) { return 1.0f / (1.0f + __expf(-x)); }
__device__ __forceinline__ float tanhff(float x) {
    return 1.0f - 2.0f / (__expf(2.0f * x) + 1.0f);
}

// ---- pack W_hh (4096x1024 f32) -> fp16 B-fragment order ----
// Wp[jt2(32)][kc(32)][g(4)][nt(2)][lane(64)][8] ; per-jt2 block = 256 KB
__global__ __launch_bounds__(256) void pack_w(const float* __restrict__ W_hh,
                                              unsigned short* __restrict__ Wp) {
    int fid = blockIdx.x * 256 + threadIdx.x;   // 0..524287
    int lane = fid & 63;
    int nt = (fid >> 6) & 1;
    int g = (fid >> 7) & 3;
    int kc = (fid >> 9) & 31;
    int jt2 = fid >> 14;
    int j = jt2 * 32 + nt * 16 + (lane & 15);
    int row = g * HH + j;
    int k = kc * 32 + (lane >> 4) * 8;
    const float* src = W_hh + (size_t)row * HH + k;
    union { _Float16 h[8]; short8 s; } u;
#pragma unroll
    for (int e = 0; e < 8; ++e) u.h[e] = (_Float16)src[e];
    *(short8*)(Wp + (size_t)fid * 8) = u.s;
}

// ---- h0 -> fp16 fragment layout in buffer 0; zero barrier counters ----
// unit U=(k>>5)*8+((k>>2)&7); u64 idx = U*256 + M  (boff == M)
__global__ __launch_bounds__(256) void prep_state(const float* __restrict__ h0,
                                                  unsigned long long* __restrict__ hb0,
                                                  unsigned int* __restrict__ cnt) {
    int gid = blockIdx.x * 256 + threadIdx.x;   // 0..65535
    int r = gid & 255;
    int U = gid >> 8;
    int kb = (U >> 3) * 32 + ((U >> 1) & 3) * 8 + (U & 1) * 4;
    float4 v = *(const float4*)(h0 + (size_t)r * HH + kb);
    union { _Float16 h[4]; unsigned long long u; } x;
    x.h[0] = (_Float16)v.x; x.h[1] = (_Float16)v.y;
    x.h[2] = (_Float16)v.z; x.h[3] = (_Float16)v.w;
    hb0[(size_t)U * 256 + r] = x.u;
    if (blockIdx.x == 0) cnt[threadIdx.x] = 0;   // 256 u32 = 8 groups x 32
}

// ---- persistent LSTM kernel: all 512 steps + final FC ----
__global__ __launch_bounds__(512, 1) void lstm_persist(
    const float* __restrict__ y_hist,
    const float* __restrict__ W_ih,           // (4096) flat
    const float* __restrict__ b_ih,
    const float* __restrict__ b_hh,
    const float* __restrict__ c0,             // (B,H) f32
    const float* __restrict__ W_fc,           // (H)
    const float* __restrict__ b_fc,           // (1)
    const unsigned short* __restrict__ Wp,    // packed fp16 W fragments
    unsigned long long* hbase,                // 2 buffers x HP_U64 u64
    unsigned int* cnt,
    float* __restrict__ out)
{
    __shared__ __align__(16) unsigned short Wlds[65536];   // 128 KB: gates 0,1
    __shared__ __align__(16) float scr[8192];              // 32 KB: 4 regions x 2048
    // 160 KiB exactly -> 1 WG/CU; grid=256 => all WGs co-resident

    const int tid = threadIdx.x;
    const int lane = tid & 63;
    const int wv = tid >> 6;
    const int m2 = wv & 1;                     // m half (16 rows)
    const int k4 = wv >> 1;                    // K quarter (256 k)
    const int bid = blockIdx.x;
    const int gm = bid >> 5;                   // m-group 0..7 (32 rows)
    const int jt2 = bid & 31;                  // 32-j tile

    const unsigned short* WpJ = Wp + (size_t)jt2 * 131072;

    // --- LDS: gates 0,1 fragments (all kc) ---
    for (int f = tid; f < 8192; f += 512) {
        int kc = f >> 8, g = (f >> 7) & 1, low = f & 127;
        *(short8*)&Wlds[(size_t)((kc * 2 + g) * 128 + low) * 8] =
            *(const short8*)(WpJ + (size_t)((kc * 4 + g) * 128 + low) * 8);
    }
    // --- registers: gates 2,3 fragments for this wave's K-quarter ---
    half8 Breg[8][2][2];   // [kc_l][g-2][nt]
#pragma unroll
    for (int kc_l = 0; kc_l < 8; ++kc_l) {
        int kc = k4 * 8 + kc_l;
#pragma unroll
        for (int g2 = 0; g2 < 2; ++g2)
#pragma unroll
            for (int nt = 0; nt < 2; ++nt)
                Breg[kc_l][g2][nt] = *(const half8*)
                    (WpJ + (size_t)((((kc * 4 + 2 + g2) * 2 + nt) * 64 + lane)) * 8);
    }

    // --- A addressing ---
    const int blk = gm * 2 + m2;               // 16-row block 0..15
    const int q = lane >> 4;
    const size_t abase = (size_t)blk * 16 + (lane & 15);
    const size_t qoff = (size_t)q * 512;

    // --- epilogue constants (ALL 512 threads: cell = 1 row x 2 j) ---
    const int em = tid & 31;                   // tile-local row
    const int jp = tid >> 5;                   // j-pair 0..15
    const int jq = jp >> 1;
    const int M = gm * 32 + em;
    float wi_[4][2], bs_[4][2], c_[2];
#pragma unroll
    for (int g = 0; g < 4; ++g)
#pragma unroll
        for (int jj = 0; jj < 2; ++jj) {
            int j = jt2 * 32 + jp * 2 + jj;
            wi_[g][jj] = W_ih[g * HH + j];
            bs_[g][jj] = b_ih[g * HH + j] + b_hh[g * HH + j];
        }
#pragma unroll
    for (int jj = 0; jj < 2; ++jj)
        c_[jj] = c0[(size_t)M * HH + jt2 * 32 + jp * 2 + jj];
    // u32 store index: ((jt2*8+jq)*256 + M)*2 + (jp&1); wave = full 256B line
    const size_t sidx32 = ((size_t)(jt2 * 8 + jq) * 256 + M) * 2 + (jp & 1);

    __syncthreads();   // Wlds visible

    unsigned int* mycnt = cnt + gm * 32;
    const int ml = q * 4;                      // local row base within 16-row tile

    for (int t = 0; t < TT; ++t) {
        const unsigned long long* hR = hbase + (size_t)(t & 1) * HP_U64;
        unsigned long long* hW = hbase + (size_t)((t + 1) & 1) * HP_U64;

        // prefetch y_hist x (consumed in epilogue; hides under K-loop)
        float x = y_hist[(size_t)M * TT + t];

        float4v acc[8] = {{0.f,0.f,0.f,0.f},{0.f,0.f,0.f,0.f},{0.f,0.f,0.f,0.f},
                          {0.f,0.f,0.f,0.f},{0.f,0.f,0.f,0.f},{0.f,0.f,0.f,0.f},
                          {0.f,0.f,0.f,0.f},{0.f,0.f,0.f,0.f}};

        // --- sync-free K-loop: 8 chunks of K=32, FULL 8-deep prefetch ring ---
        unsigned long long ring[8][2];
#pragma unroll
        for (int p = 0; p < 8; ++p) {
            size_t ua = (size_t)(k4 * 8 + p) * 2048 + qoff + abase;
            ring[p][0] = __hip_atomic_load((unsigned long long*)&hR[ua],
                                           __ATOMIC_RELAXED, __HIP_MEMORY_SCOPE_AGENT);
            ring[p][1] = __hip_atomic_load((unsigned long long*)&hR[ua + 256],
                                           __ATOMIC_RELAXED, __HIP_MEMORY_SCOPE_AGENT);
        }
#pragma unroll
        for (int ch = 0; ch < 8; ++ch) {
            union { unsigned long long u[2]; half8 h; } af;
            af.u[0] = ring[ch][0];
            af.u[1] = ring[ch][1];
            const int kc = k4 * 8 + ch;
#pragma unroll
            for (int g = 0; g < 2; ++g)
#pragma unroll
                for (int nt = 0; nt < 2; ++nt) {
                    half8 bh = *(const half8*)
                        &Wlds[(size_t)((kc * 2 + g) * 128 + nt * 64 + lane) * 8];
                    acc[g * 2 + nt] =
                        __builtin_amdgcn_mfma_f32_16x16x32_f16(af.h, bh, acc[g * 2 + nt], 0, 0, 0);
                }
#pragma unroll
            for (int g2 = 0; g2 < 2; ++g2)
#pragma unroll
                for (int nt = 0; nt < 2; ++nt)
                    acc[(2 + g2) * 2 + nt] =
                        __builtin_amdgcn_mfma_f32_16x16x32_f16(af.h, Breg[ch][g2][nt],
                                                               acc[(2 + g2) * 2 + nt], 0, 0, 0);
        }

        // --- 4-way k-reduction, 2 rounds in 32 KB scratch (v6-proven) ---
        if (k4 >= 2) {
            int rb = (m2 * 2 + (k4 & 1)) * 2048;
#pragma unroll
            for (int a = 0; a < 8; ++a) {
                int n = (a >> 1) * 32 + (a & 1) * 16 + (lane & 15);
                *(float4v*)&scr[rb + n * 16 + (ml ^ ((n & 3) << 2))] = acc[a];
            }
        }
        __syncthreads();
        if (k4 < 2) {
            int rb = (m2 * 2 + k4) * 2048;
#pragma unroll
            for (int a = 0; a < 8; ++a) {
                int n = (a >> 1) * 32 + (a & 1) * 16 + (lane & 15);
                acc[a] += *(const float4v*)&scr[rb + n * 16 + (ml ^ ((n & 3) << 2))];
            }
            if (k4 == 1) {
#pragma unroll
                for (int a = 0; a < 8; ++a) {
                    int n = (a >> 1) * 32 + (a & 1) * 16 + (lane & 15);
                    *(float4v*)&scr[(m2 * 2 + 1) * 2048 + n * 16 + (ml ^ ((n & 3) << 2))] = acc[a];
                }
            }
        }
        __syncthreads();
        if (k4 == 0) {
#pragma unroll
            for (int a = 0; a < 8; ++a) {
                int n = (a >> 1) * 32 + (a & 1) * 16 + (lane & 15);
                int sw = n * 16 + (ml ^ ((n & 3) << 2));
                acc[a] += *(const float4v*)&scr[(m2 * 2 + 1) * 2048 + sw];
                *(float4v*)&scr[(m2 * 2) * 2048 + sw] = acc[a];
            }
        }
        __syncthreads();

        // --- epilogue (all 512 threads): 1 row x 2 j; one u32 sc0sc1 store ---
        {
            int rbase = (em >> 4) * 2 * 2048;
            union { _Float16 h[2]; unsigned int u; } hv;
#pragma unroll
            for (int jj = 0; jj < 2; ++jj) {
                int jl = jp * 2 + jj;                      // 0..31
                int msw = (em & 15) ^ ((jl & 3) << 2);
                float gi = scr[rbase + (0 * 32 + jl) * 16 + msw] + x * wi_[0][jj] + bs_[0][jj];
                float gf = scr[rbase + (1 * 32 + jl) * 16 + msw] + x * wi_[1][jj] + bs_[1][jj];
                float gg = scr[rbase + (2 * 32 + jl) * 16 + msw] + x * wi_[2][jj] + bs_[2][jj];
                float go = scr[rbase + (3 * 32 + jl) * 16 + msw] + x * wi_[3][jj] + bs_[3][jj];
                float cn = sigf(gf) * c_[jj] + sigf(gi) * tanhff(gg);
                float hn = sigf(go) * tanhff(cn);
                c_[jj] = cn;
                hv.h[jj] = (_Float16)hn;
            }
            asm volatile("global_store_dword %0, %1, off sc0 sc1"
                         : : "v"((void*)((unsigned int*)hW + sidx32)), "v"(hv.u) : "memory");
        }

        // --- drain stores, then m-group barrier (32 WGs, v6-proven) ---
        asm volatile("s_waitcnt vmcnt(0)" ::: "memory");
        __syncthreads();
        if (tid == 0) {
            __hip_atomic_fetch_add(mycnt, 1u, __ATOMIC_RELAXED, __HIP_MEMORY_SCOPE_AGENT);
            unsigned target = 32u * (unsigned)(t + 1);
            while (__hip_atomic_load(mycnt, __ATOMIC_RELAXED, __HIP_MEMORY_SCOPE_AGENT) <
                   target)
                __builtin_amdgcn_s_sleep(1);
        }
        __syncthreads();
    }

    // --- final FC (h final in buffer 0): jt2==0 WGs, k4==0 waves ---
    if (jt2 == 0 && k4 == 0) {
        const unsigned long long* hF = hbase;   // buffer 0
#pragma unroll 1
        for (int rr = 0; rr < 16; ++rr) {
            int row = gm * 32 + m2 * 16 + rr;
            int boff = row;                     // boff == M
            float s = 0.f;
#pragma unroll 1
            for (int uu = 0; uu < 4; ++uu) {
                int U = uu * 64 + lane;
                unsigned long long u = __hip_atomic_load(
                    (unsigned long long*)&hF[(size_t)U * 256 + boff],
                    __ATOMIC_RELAXED, __HIP_MEMORY_SCOPE_AGENT);
                int kb = (U >> 3) * 32 + ((U >> 1) & 3) * 8 + (U & 1) * 4;
                union { _Float16 h[4]; unsigned long long x; } v;
                v.x = u;
                float4 wf = *(const float4*)(W_fc + kb);
                s += (float)v.h[0] * wf.x + (float)v.h[1] * wf.y +
                     (float)v.h[2] * wf.z + (float)v.h[3] * wf.w;
            }
#pragma unroll
            for (int off = 32; off > 0; off >>= 1) s += __shfl_xor(s, off);
            if (lane == 0) out[row] = s + b_fc[0];
        }
    }
}

extern "C" void kernel_launch(void* const* d_in, const int* in_sizes, int n_in,
                              void* d_out, int out_size, void* d_ws, size_t ws_size,
                              hipStream_t stream) {
    const float* y_hist = (const float*)d_in[0];
    const float* W_ih   = (const float*)d_in[1];
    const float* W_hh   = (const float*)d_in[2];
    const float* b_ih   = (const float*)d_in[3];
    const float* b_hh   = (const float*)d_in[4];
    const float* W_fc   = (const float*)d_in[5];
    const float* b_fc   = (const float*)d_in[6];
    const float* h0     = (const float*)d_in[7];
    const float* c0     = (const float*)d_in[8];
    float* out = (float*)d_out;

    // ws: Wp fp16 (8 MB) | h buffers 2 x 512 KB | cnt (1 KB)
    unsigned short* Wp = (unsigned short*)d_ws;
    unsigned long long* hbase = (unsigned long long*)(Wp + (size_t)4194304);
    unsigned int* cnt = (unsigned int*)(hbase + 2 * HP_U64);

    pack_w<<<2048, 256, 0, stream>>>(W_hh, Wp);
    prep_state<<<256, 256, 0, stream>>>(h0, hbase, cnt);

    // 256 WGs x 512 threads, 160 KiB LDS -> 1 WG/CU, all co-resident
    lstm_persist<<<256, 512, 0, stream>>>(y_hist, W_ih, b_ih, b_hh, c0, W_fc, b_fc,
                                          Wp, hbase, cnt, out);
}